// Round 13
// baseline (642.264 us; speedup 1.0000x reference)
//
#include <hip/hip_runtime.h>
#include <stdint.h>

#define H_DIM 768
#define N_SUP 32768
#define Q_QRY 32768
#define C_CLS 10
#define M_TOT 65536   // spans total; also token count
#define KG 768        // GEMM K
#define NG 2304       // GEMM N (=3*H)
#define NT 12         // K tiles of 64
#define NBUCK 1024

typedef __bf16 bf16x8 __attribute__((ext_vector_type(8)));
typedef float f32x4 __attribute__((ext_vector_type(4)));
typedef __attribute__((address_space(3))) void lds_void;
typedef const __attribute__((address_space(1))) void g_void;

__device__ __forceinline__ ushort f2bf(float f) {
  union { float f; uint32_t u; } v; v.f = f;
  uint32_t r = (v.u + 0x7FFFu + ((v.u >> 16) & 1u)) >> 16;
  return (ushort)r;
}
__device__ __forceinline__ float bf2f(ushort h) {
  union { uint32_t u; float f; } v; v.u = ((uint32_t)h) << 16; return v.f;
}
__device__ __forceinline__ float gelu_f(float x) {
  return 0.5f * x * (1.0f + erff(x * 0.70710678118654752f));
}

// ---------------- prep: cvt (24576 blks) + wt2 (6912 blks) + hist (64 blks) ----------------
__global__ void prep_kernel(const float* __restrict__ te, const float* __restrict__ W,
                            const int* __restrict__ spS, const int* __restrict__ spQ,
                            ushort* __restrict__ tb, ushort* __restrict__ Bt,
                            int* __restrict__ histS, int* __restrict__ histQ) {
  int b = blockIdx.x, t = threadIdx.x;
  if (b < 24576) {
    size_t i = (((size_t)b * 256) + t) * 8;
    float4 v0 = *(const float4*)(te + i);
    float4 v1 = *(const float4*)(te + i + 4);
    uint4 o;
    o.x = ((uint32_t)f2bf(v0.y) << 16) | f2bf(v0.x);
    o.y = ((uint32_t)f2bf(v0.w) << 16) | f2bf(v0.z);
    o.z = ((uint32_t)f2bf(v1.y) << 16) | f2bf(v1.x);
    o.w = ((uint32_t)f2bf(v1.w) << 16) | f2bf(v1.z);
    *(uint4*)(tb + i) = o;
  } else if (b < 31488) {
    int idx = (b - 24576) * 256 + t;   // < 2304*768
    int n = idx / KG, k = idx - n * KG;
    int blk = n / H_DIM;
    int c = n - blk * H_DIM;
    Bt[idx] = f2bf(W[(size_t)(blk * H_DIM + k) * H_DIM + c]);
  } else {
    __shared__ int lhS[NBUCK], lhQ[NBUCK];
    for (int i = t; i < NBUCK; i += 256) { lhS[i] = 0; lhQ[i] = 0; }
    __syncthreads();
    int b0 = b - 31488;   // 0..63
    for (int i = b0 * 256 + t; i < N_SUP; i += 64 * 256) {
      atomicAdd(&lhS[spS[2 * i] >> 6], 1);
      atomicAdd(&lhQ[spQ[2 * i] >> 6], 1);
    }
    __syncthreads();
    for (int i = t; i < NBUCK; i += 256) {
      if (lhS[i]) atomicAdd(&histS[i], lhS[i]);
      if (lhQ[i]) atomicAdd(&histQ[i], lhQ[i]);
    }
  }
}

// ---------------- exclusive prefix for both hists ----------------
__global__ void prefix2_kernel(const int* __restrict__ histS, const int* __restrict__ histQ,
                               int* __restrict__ curS, int* __restrict__ curQ) {
  __shared__ int tmp[NBUCK];
  int t = threadIdx.x;
  {
    int v = histS[t];
    tmp[t] = v;
    __syncthreads();
    for (int off = 1; off < NBUCK; off <<= 1) {
      int add = (t >= off) ? tmp[t - off] : 0;
      __syncthreads();
      tmp[t] += add;
      __syncthreads();
    }
    curS[t] = tmp[t] - v;
    __syncthreads();
  }
  {
    int v = histQ[t];
    tmp[t] = v;
    __syncthreads();
    for (int off = 1; off < NBUCK; off <<= 1) {
      int add = (t >= off) ? tmp[t - off] : 0;
      __syncthreads();
      tmp[t] += add;
      __syncthreads();
    }
    curQ[t] = tmp[t] - v;
  }
}

// ---------------- scatter both span sets into start-sorted order ----------------
__global__ void scatter2_kernel(const int* __restrict__ spS, const int* __restrict__ spQ,
                                int* __restrict__ curS, int* __restrict__ curQ,
                                int2* __restrict__ sortedS, int2* __restrict__ sortedQ) {
  for (int i = blockIdx.x * 256 + threadIdx.x; i < N_SUP; i += gridDim.x * 256) {
    {
      int s = spS[2 * i], e = spS[2 * i + 1];
      int pos = atomicAdd(&curS[s >> 6], 1);
      int2 rec; rec.x = s; rec.y = (i << 5) | (e - s);
      sortedS[pos] = rec;
    }
    {
      int s = spQ[2 * i], e = spQ[2 * i + 1];
      int pos = atomicAdd(&curQ[s >> 6], 1);
      int2 rec; rec.x = s; rec.y = (i << 5) | (e - s);
      sortedQ[pos] = rec;
    }
  }
}

// ---------------- 128x128 4-wave phase-pipelined GEMM (R2 schedule geometry-ported): ----------------
// 64 KB LDS -> 2 blocks/CU co-resident; independent barrier groups overlap
// prologue/epilogue/barrier stalls across blocks. Ledger: 3 K-halves in flight,
// vmcnt(8) every phase (stage group = 4 loads/thread).
__global__ __launch_bounds__(256, 2) void gemm4(const ushort* __restrict__ A,
                                                const ushort* __restrict__ Bt,
                                                ushort* __restrict__ C) {
  __shared__ ushort lds[32768];  // 64 KB
  char* ldsc = (char*)lds;

  int orig = blockIdx.x;
  int wg = (orig & 7) * 1152 + (orig >> 3);  // nwg=9216 = 8*1152, bijective XCD swizzle
  int rowT = wg / 18, colT = wg - rowT * 18; // 18 consecutive wgs share one A panel
  int m0 = rowT * 128, n0 = colT * 128;

  int tid = threadIdx.x;
  int lane = tid & 63, wave = tid >> 6;
  int wr = wave >> 1, wc = wave & 1;         // 2x2 wave grid; per-wave C = 64x64
  int l15 = lane & 15, l4 = lane >> 4;

  int row0 = tid >> 2;                        // 0..63 (L=0); L=1 adds 64
  int ss = (tid & 3) ^ ((row0 >> 1) & 3);     // same for row+64 (64>>1 % 4 == 0)
  size_t eA0 = (size_t)(m0 + row0) * KG + ss * 8;
  size_t eA1 = (size_t)(m0 + row0 + 64) * KG + ss * 8;
  size_t eB0 = (size_t)(n0 + row0) * KG + ss * 8;
  size_t eB1 = (size_t)(n0 + row0 + 64) * KG + ss * 8;

  // ds_read byte offsets within an 8 KB slot (128 rows x 64 B)
  int aoff[4], boff[4];
#pragma unroll
  for (int m = 0; m < 4; ++m) {
    int r = wr * 64 + m * 16 + l15;
    aoff[m] = r * 64 + ((l4 ^ ((r >> 1) & 3)) << 4);
  }
#pragma unroll
  for (int n = 0; n < 4; ++n) {
    int r = wc * 64 + n * 16 + l15;
    boff[n] = r * 64 + ((l4 ^ ((r >> 1) & 3)) << 4);
  }

  f32x4 acc[4][4];
#pragma unroll
  for (int m = 0; m < 4; ++m)
#pragma unroll
    for (int n = 0; n < 4; ++n) acc[m][n] = (f32x4){0.f, 0.f, 0.f, 0.f};

#define SLOT_A(kh, db) (ldsc + ((kh) * 2 + (db)) * 8192)
#define SLOT_B(kh, db) (ldsc + 32768 + ((kh) * 2 + (db)) * 8192)
// one stage group = A-half + B-half of one kh (4 x global_load_lds per thread)
#define SAB(tk, kh, db) do { \
    char* _da = SLOT_A(kh, db) + wave * 1024; \
    char* _db2 = SLOT_B(kh, db) + wave * 1024; \
    size_t _k = (size_t)(tk) * 64 + (kh) * 32; \
    __builtin_amdgcn_global_load_lds((g_void*)(A + eA0 + _k), (lds_void*)_da, 16, 0, 0); \
    __builtin_amdgcn_global_load_lds((g_void*)(A + eA1 + _k), (lds_void*)(_da + 4096), 16, 0, 0); \
    __builtin_amdgcn_global_load_lds((g_void*)(Bt + eB0 + _k), (lds_void*)_db2, 16, 0, 0); \
    __builtin_amdgcn_global_load_lds((g_void*)(Bt + eB1 + _k), (lds_void*)(_db2 + 4096), 16, 0, 0); \
  } while (0)
#define LDA4(base) do { _Pragma("unroll") for (int m = 0; m < 4; ++m) \
    af[m] = *reinterpret_cast<const bf16x8*>((base) + aoff[m]); } while (0)
#define LDB4(base) do { _Pragma("unroll") for (int n = 0; n < 4; ++n) \
    bf[n] = *reinterpret_cast<const bf16x8*>((base) + boff[n]); } while (0)
#define MFMA16() do { _Pragma("unroll") for (int m = 0; m < 4; ++m) \
  _Pragma("unroll") for (int n = 0; n < 4; ++n) \
    acc[m][n] = __builtin_amdgcn_mfma_f32_16x16x32_bf16(af[m], bf[n], acc[m][n], 0, 0, 0); \
  } while (0)
#define BARX() __builtin_amdgcn_s_barrier()
#define LGKM0() asm volatile("s_waitcnt lgkmcnt(0)" ::: "memory")
#define VM8() asm volatile("s_waitcnt vmcnt(8)" ::: "memory")

  // prologue: kh0(0), kh1(0), kh0(1); VM8 -> kh0(0) landed, 8 in flight
  SAB(0, 0, 0);
  SAB(0, 1, 0);
  SAB(1, 0, 1);
  VM8();
  BARX();

  bf16x8 af[4], bf[4];
  for (int t = 0; t < NT; ++t) {
    int d = t & 1, nd = d ^ 1;
    int tk1 = (t + 1 < NT) ? t + 1 : NT - 1;   // clamped targets write dead slots only
    int tk2 = (t + 2 < NT) ? t + 2 : NT - 1;
    // P1: kh0
    LDA4(SLOT_A(0, d)); LDB4(SLOT_B(0, d));
    SAB(tk1, 1, nd);
    BARX(); LGKM0();
    __builtin_amdgcn_s_setprio(1); MFMA16(); __builtin_amdgcn_s_setprio(0);
    VM8();   // drains kh1(t) -> ready for P2
    BARX();
    // P2: kh1
    LDA4(SLOT_A(1, d)); LDB4(SLOT_B(1, d));
    SAB(tk2, 0, d);
    BARX(); LGKM0();
    __builtin_amdgcn_s_setprio(1); MFMA16(); __builtin_amdgcn_s_setprio(0);
    VM8();   // drains kh0(t+1) -> ready for next P1
    BARX();
  }
  asm volatile("s_waitcnt vmcnt(0)" ::: "memory");

  // epilogue: raw bf16 C store (R2-style)
#pragma unroll
  for (int m = 0; m < 4; ++m)
#pragma unroll
    for (int n = 0; n < 4; ++n) {
      int col = n0 + wc * 64 + n * 16 + l15;
      size_t rb = (size_t)(m0 + wr * 64 + m * 16 + l4 * 4) * NG + col;
#pragma unroll
      for (int v = 0; v < 4; ++v)
        C[rb + (size_t)v * NG] = f2bf(acc[m][n][v]);
    }
#undef SLOT_A
#undef SLOT_B
#undef SAB
#undef LDA4
#undef LDB4
#undef MFMA16
}

// ---------------- shared span-embed core (R6 combine2 math) ----------------
__device__ __forceinline__ void span_embed(const ushort* __restrict__ PQR,
                                           const float* __restrict__ bias,
                                           int s, int len, int lane, float x[3][4]) {
  int e = s + len;
  float inv = 1.0f / (float)len;
  float acc0[3][4], accr[3][4];
  const ushort* Pr = PQR + (size_t)s * NG;
  const ushort* Qr = PQR + (size_t)(e - 1) * NG + 768;
#pragma unroll
  for (int c = 0; c < 3; ++c) {
    int h = c * 256 + lane * 4;
    ushort4 p = *(const ushort4*)(Pr + h);
    ushort4 q = *(const ushort4*)(Qr + h);
    acc0[c][0] = bf2f(p.x) + bf2f(q.x);
    acc0[c][1] = bf2f(p.y) + bf2f(q.y);
    acc0[c][2] = bf2f(p.z) + bf2f(q.z);
    acc0[c][3] = bf2f(p.w) + bf2f(q.w);
    accr[c][0] = accr[c][1] = accr[c][2] = accr[c][3] = 0.f;
  }
  for (int r = s; r < e; ++r) {
    const ushort* Rr = PQR + (size_t)r * NG + 1536;
#pragma unroll
    for (int c = 0; c < 3; ++c) {
      int h = c * 256 + lane * 4;
      ushort4 rv = *(const ushort4*)(Rr + h);
      accr[c][0] += bf2f(rv.x); accr[c][1] += bf2f(rv.y);
      accr[c][2] += bf2f(rv.z); accr[c][3] += bf2f(rv.w);
    }
  }
#pragma unroll
  for (int c = 0; c < 3; ++c) {
    int h = c * 256 + lane * 4;
    float4 bv = *(const float4*)(bias + h);
    x[c][0] = gelu_f(acc0[c][0] + accr[c][0] * inv + bv.x);
    x[c][1] = gelu_f(acc0[c][1] + accr[c][1] * inv + bv.y);
    x[c][2] = gelu_f(acc0[c][2] + accr[c][2] * inv + bv.z);
    x[c][3] = gelu_f(acc0[c][3] + accr[c][3] * inv + bv.w);
  }
}

// ---------------- support combine (R10 verbatim): writes embS ----------------
__global__ __launch_bounds__(256) void combine_sup(const ushort* __restrict__ PQR,
                                                   const int2* __restrict__ sortedS,
                                                   const float* __restrict__ bias,
                                                   ushort* __restrict__ embS) {
  int b = blockIdx.x;                        // 8192 blocks
  int sb = ((b & 7) << 10) + (b >> 3);       // XCD-contiguous chunks of 1024 blocks
  int wave = threadIdx.x >> 6, lane = threadIdx.x & 63;
  int wid = sb * 4 + wave;                   // 0..32767
  int2 rec = sortedS[wid];
  int s = rec.x, len = rec.y & 31, orig = rec.y >> 5;
  float x[3][4];
  span_embed(PQR, bias, s, len, lane, x);
  ushort* er = embS + (size_t)orig * H_DIM;
#pragma unroll
  for (int c = 0; c < 3; ++c) {
    int h = c * 256 + lane * 4;
    ushort4 o;
    o.x = f2bf(x[c][0]); o.y = f2bf(x[c][1]); o.z = f2bf(x[c][2]); o.w = f2bf(x[c][3]);
    *(ushort4*)(er + h) = o;
  }
}

// ---------------- proto accumulation: 1024 blocks x 32 spans ----------------
__global__ void proto_accum(const ushort* __restrict__ supEmb, const int* __restrict__ labels,
                            float* __restrict__ pSum, float* __restrict__ pCnt) {
  __shared__ float ls[C_CLS * H_DIM];
  __shared__ int lc[C_CLS];
  int t = threadIdx.x;
  for (int i = t; i < C_CLS * H_DIM; i += 256) ls[i] = 0.f;
  if (t < C_CLS) lc[t] = 0;
  __syncthreads();
  int base = blockIdx.x * 32;
  for (int si = 0; si < 32; ++si) {
    int sp = base + si;
    int lab = labels[sp];
    const ushort* er = supEmb + (size_t)sp * H_DIM;
#pragma unroll
    for (int j = 0; j < 3; ++j) {
      int c = t + j * 256;
      ls[lab * H_DIM + c] += bf2f(er[c]);
    }
    if (t == 0) lc[lab]++;
  }
  __syncthreads();
  for (int i = t; i < C_CLS * H_DIM; i += 256) atomicAdd(&pSum[i], ls[i]);
  if (t < C_CLS) atomicAdd(&pCnt[t], (float)lc[t]);
}

// ---------------- proto normalize (1 block) ----------------
__global__ void proto_norm(const float* __restrict__ pSum, const float* __restrict__ pCnt,
                           float* __restrict__ pN) {
  __shared__ float red[4];
  int t = threadIdx.x, lane = t & 63, wave = t >> 6;
  for (int c = 0; c < C_CLS; ++c) {
    float cnt = pCnt[c];
    float x[3];
#pragma unroll
    for (int j = 0; j < 3; ++j) {
      int h = t + j * 256;
      float v;
      if (cnt > 0.5f) v = pSum[c * H_DIM + h] / cnt;
      else {
        float gs = 0.f;
        for (int cc = 0; cc < C_CLS; ++cc) gs += pSum[cc * H_DIM + h];
        v = gs / (float)N_SUP;
      }
      x[j] = v;
    }
    float ss = x[0] * x[0] + x[1] * x[1] + x[2] * x[2];
#pragma unroll
    for (int o = 32; o; o >>= 1) ss += __shfl_xor(ss, o);
    if (lane == 0) red[wave] = ss;
    __syncthreads();
    float tot = red[0] + red[1] + red[2] + red[3];
    float inv = 1.0f / fmaxf(sqrtf(tot), 1e-12f);
#pragma unroll
    for (int j = 0; j < 3; ++j) pN[c * H_DIM + t + j * 256] = x[j] * inv;
    __syncthreads();
  }
}

// ---------------- query: embed + sim fused (R10 verbatim) ----------------
__global__ __launch_bounds__(256) void combine_qry_sim(const ushort* __restrict__ PQR,
                                                       const int2* __restrict__ sortedQ,
                                                       const float* __restrict__ bias,
                                                       const float* __restrict__ pN,
                                                       float* __restrict__ out) {
  __shared__ float lp[C_CLS * H_DIM];
  int b = blockIdx.x;                        // 8192 blocks
  int sb = ((b & 7) << 10) + (b >> 3);       // XCD-contiguous chunks of 1024 blocks
  int t = threadIdx.x, lane = t & 63, wave = t >> 6;
  for (int i = t; i < C_CLS * H_DIM; i += 256) lp[i] = pN[i];
  __syncthreads();
  int wid = sb * 4 + wave;                   // 0..32767
  int2 rec = sortedQ[wid];
  int s = rec.x, len = rec.y & 31, orig = rec.y >> 5;
  float x[3][4];
  span_embed(PQR, bias, s, len, lane, x);
  float sq = 0.f;
  float dot[C_CLS];
#pragma unroll
  for (int p = 0; p < C_CLS; ++p) dot[p] = 0.f;
#pragma unroll
  for (int c = 0; c < 3; ++c) {
    int h = c * 256 + lane * 4;
    sq += x[c][0] * x[c][0] + x[c][1] * x[c][1] + x[c][2] * x[c][2] + x[c][3] * x[c][3];
#pragma unroll
    for (int p = 0; p < C_CLS; ++p) {
      float4 pv = *(const float4*)(lp + p * H_DIM + h);
      dot[p] += x[c][0] * pv.x + x[c][1] * pv.y + x[c][2] * pv.z + x[c][3] * pv.w;
    }
  }
#pragma unroll
  for (int o = 32; o; o >>= 1) {
    sq += __shfl_xor(sq, o);
#pragma unroll
    for (int p = 0; p < C_CLS; ++p) dot[p] += __shfl_xor(dot[p], o);
  }
  if (lane == 0) {
    float inv = 1.0f / fmaxf(sqrtf(sq), 1e-12f);
    float* o = out + (size_t)orig * (C_CLS + 1);
    o[0] = dot[0] * inv; o[1] = dot[1] * inv; o[2] = dot[2] * inv;
    o[3] = dot[3] * inv; o[4] = dot[4] * inv; o[5] = dot[5] * inv;
    o[6] = dot[6] * inv; o[7] = dot[7] * inv; o[8] = dot[8] * inv;
    o[9] = dot[9] * inv; o[10] = 0.5f;
  }
}

extern "C" void kernel_launch(void* const* d_in, const int* in_sizes, int n_in,
                              void* d_out, int out_size, void* d_ws, size_t ws_size,
                              hipStream_t stream) {
  const float* token_emb = (const float*)d_in[0];
  const int*   spansS    = (const int*)d_in[1];
  const int*   labels    = (const int*)d_in[2];
  const int*   spansQ    = (const int*)d_in[3];
  const float* W         = (const float*)d_in[4];
  const float* b         = (const float*)d_in[5];
  float* out = (float*)d_out;

  char* ws = (char*)d_ws;
  size_t pqrB = (size_t)M_TOT * NG * 2;        // 301,989,888
  size_t tbB  = (size_t)M_TOT * H_DIM * 2;     // 100,663,296
  size_t wtB  = (size_t)NG * KG * 2;           //   3,538,944
  ushort* PQR  = (ushort*)ws;
  ushort* tebf = (ushort*)(ws + pqrB);         // dead after gemm4
  ushort* embS = tebf;                          // support embeddings alias tebf
  ushort* Bt   = (ushort*)(ws + pqrB + tbB);
  char*   tail = ws + pqrB + tbB + wtB;
  float*  pSum = (float*)tail;                                  // 7680 f
  float*  pCnt = pSum + C_CLS * H_DIM;                          // 64 f
  float*  pN   = pCnt + 64;                                     // 7680 f
  int*    histS = (int*)(pN + C_CLS * H_DIM);                   // 1024
  int*    histQ = histS + NBUCK;                                // 1024
  int*    curS  = histQ + NBUCK;                                // 1024
  int*    curQ  = curS + NBUCK;                                 // 1024
  int2*   sortedS = (int2*)(curQ + NBUCK);                      // 32768 int2
  int2*   sortedQ = sortedS + N_SUP;                            // 32768 int2

  hipMemsetAsync(pSum, 0, (C_CLS * H_DIM + 64) * sizeof(float), stream);
  hipMemsetAsync(histS, 0, 2 * NBUCK * sizeof(int), stream);
  prep_kernel<<<31552, 256, 0, stream>>>(token_emb, W, spansS, spansQ, tebf, Bt, histS, histQ);
  prefix2_kernel<<<1, NBUCK, 0, stream>>>(histS, histQ, curS, curQ);
  scatter2_kernel<<<64, 256, 0, stream>>>(spansS, spansQ, curS, curQ, sortedS, sortedQ);
  gemm4<<<9216, 256, 0, stream>>>(tebf, Bt, PQR);
  combine_sup<<<8192, 256, 0, stream>>>(PQR, sortedS, b, embS);
  proto_accum<<<N_SUP / 32, 256, 0, stream>>>(embS, labels, pSum, pCnt);
  proto_norm<<<1, 256, 0, stream>>>(pSum, pCnt, pN);
  combine_qry_sim<<<8192, 256, 0, stream>>>(PQR, sortedQ, b, pN, out);
}

// Round 14
// 568.754 us; speedup vs baseline: 1.1292x; 1.1292x over previous
//
#include <hip/hip_runtime.h>
#include <stdint.h>

#define H_DIM 768
#define N_SUP 32768
#define Q_QRY 32768
#define C_CLS 10
#define M_TOT 65536   // spans total; also token count
#define KG 768        // GEMM K
#define NG 2304       // GEMM N (=3*H)
#define NT 12         // K tiles of 64
#define NBUCK 1024

typedef __bf16 bf16x8 __attribute__((ext_vector_type(8)));
typedef float f32x4 __attribute__((ext_vector_type(4)));
typedef __attribute__((address_space(3))) void lds_void;
typedef const __attribute__((address_space(1))) void g_void;

__device__ __forceinline__ ushort f2bf(float f) {
  union { float f; uint32_t u; } v; v.f = f;
  uint32_t r = (v.u + 0x7FFFu + ((v.u >> 16) & 1u)) >> 16;
  return (ushort)r;
}
__device__ __forceinline__ float bf2f(ushort h) {
  union { uint32_t u; float f; } v; v.u = ((uint32_t)h) << 16; return v.f;
}
__device__ __forceinline__ float gelu_f(float x) {
  return 0.5f * x * (1.0f + erff(x * 0.70710678118654752f));
}

// ---------------- prep: cvt (24576 blks) + wt2 (6912 blks) + hist (64 blks) ----------------
__global__ void prep_kernel(const float* __restrict__ te, const float* __restrict__ W,
                            const int* __restrict__ spS, const int* __restrict__ spQ,
                            ushort* __restrict__ tb, ushort* __restrict__ Bt,
                            int* __restrict__ histS, int* __restrict__ histQ) {
  int b = blockIdx.x, t = threadIdx.x;
  if (b < 24576) {
    size_t i = (((size_t)b * 256) + t) * 8;
    float4 v0 = *(const float4*)(te + i);
    float4 v1 = *(const float4*)(te + i + 4);
    uint4 o;
    o.x = ((uint32_t)f2bf(v0.y) << 16) | f2bf(v0.x);
    o.y = ((uint32_t)f2bf(v0.w) << 16) | f2bf(v0.z);
    o.z = ((uint32_t)f2bf(v1.y) << 16) | f2bf(v1.x);
    o.w = ((uint32_t)f2bf(v1.w) << 16) | f2bf(v1.z);
    *(uint4*)(tb + i) = o;
  } else if (b < 31488) {
    int idx = (b - 24576) * 256 + t;   // < 2304*768
    int n = idx / KG, k = idx - n * KG;
    int blk = n / H_DIM;
    int c = n - blk * H_DIM;
    Bt[idx] = f2bf(W[(size_t)(blk * H_DIM + k) * H_DIM + c]);
  } else {
    __shared__ int lhS[NBUCK], lhQ[NBUCK];
    for (int i = t; i < NBUCK; i += 256) { lhS[i] = 0; lhQ[i] = 0; }
    __syncthreads();
    int b0 = b - 31488;   // 0..63
    for (int i = b0 * 256 + t; i < N_SUP; i += 64 * 256) {
      atomicAdd(&lhS[spS[2 * i] >> 6], 1);
      atomicAdd(&lhQ[spQ[2 * i] >> 6], 1);
    }
    __syncthreads();
    for (int i = t; i < NBUCK; i += 256) {
      if (lhS[i]) atomicAdd(&histS[i], lhS[i]);
      if (lhQ[i]) atomicAdd(&histQ[i], lhQ[i]);
    }
  }
}

// ---------------- exclusive prefix for both hists ----------------
__global__ void prefix2_kernel(const int* __restrict__ histS, const int* __restrict__ histQ,
                               int* __restrict__ curS, int* __restrict__ curQ) {
  __shared__ int tmp[NBUCK];
  int t = threadIdx.x;
  {
    int v = histS[t];
    tmp[t] = v;
    __syncthreads();
    for (int off = 1; off < NBUCK; off <<= 1) {
      int add = (t >= off) ? tmp[t - off] : 0;
      __syncthreads();
      tmp[t] += add;
      __syncthreads();
    }
    curS[t] = tmp[t] - v;
    __syncthreads();
  }
  {
    int v = histQ[t];
    tmp[t] = v;
    __syncthreads();
    for (int off = 1; off < NBUCK; off <<= 1) {
      int add = (t >= off) ? tmp[t - off] : 0;
      __syncthreads();
      tmp[t] += add;
      __syncthreads();
    }
    curQ[t] = tmp[t] - v;
  }
}

// ---------------- scatter both span sets into start-sorted order ----------------
__global__ void scatter2_kernel(const int* __restrict__ spS, const int* __restrict__ spQ,
                                int* __restrict__ curS, int* __restrict__ curQ,
                                int2* __restrict__ sortedS, int2* __restrict__ sortedQ) {
  for (int i = blockIdx.x * 256 + threadIdx.x; i < N_SUP; i += gridDim.x * 256) {
    {
      int s = spS[2 * i], e = spS[2 * i + 1];
      int pos = atomicAdd(&curS[s >> 6], 1);
      int2 rec; rec.x = s; rec.y = (i << 5) | (e - s);
      sortedS[pos] = rec;
    }
    {
      int s = spQ[2 * i], e = spQ[2 * i + 1];
      int pos = atomicAdd(&curQ[s >> 6], 1);
      int2 rec; rec.x = s; rec.y = (i << 5) | (e - s);
      sortedQ[pos] = rec;
    }
  }
}

// ---------------- 256x256 8-wave 4-phase GEMM (R6 verbatim): PQR = te_bf @ Wall ----------------
__global__ __launch_bounds__(512, 2) void gemm8(const ushort* __restrict__ A,
                                                const ushort* __restrict__ Bt,
                                                ushort* __restrict__ C) {
  __shared__ ushort lds[65536];  // 128 KB
  char* ldsc = (char*)lds;

  int orig = blockIdx.x;
  int wg = (orig & 7) * 288 + (orig >> 3);   // nwg=2304 = 8*288, bijective XCD swizzle
  int rowT = wg / 9, colT = wg - rowT * 9;
  int m0 = rowT * 256, n0 = colT * 256;

  int tid = threadIdx.x;
  int lane = tid & 63, wave = tid >> 6;
  int wr = wave >> 2, wc = wave & 3;         // 2x4 wave grid; per-wave C = 128x64
  int l15 = lane & 15, l4 = lane >> 4;

  int row0 = tid >> 2;                        // 0..127 (L=0); L=1 adds 128
  int ss = (tid & 3) ^ ((row0 >> 1) & 3);
  size_t eA0 = (size_t)(m0 + row0) * KG + ss * 8;
  size_t eA1 = (size_t)(m0 + row0 + 128) * KG + ss * 8;
  size_t eB0 = (size_t)(n0 + row0) * KG + ss * 8;
  size_t eB1 = (size_t)(n0 + row0 + 128) * KG + ss * 8;

  int aoff[8], boff[4];
#pragma unroll
  for (int m = 0; m < 8; ++m) {
    int r = wr * 128 + m * 16 + l15;
    aoff[m] = r * 64 + ((l4 ^ ((r >> 1) & 3)) << 4);
  }
#pragma unroll
  for (int n = 0; n < 4; ++n) {
    int r = wc * 64 + n * 16 + l15;
    boff[n] = r * 64 + ((l4 ^ ((r >> 1) & 3)) << 4);
  }

  f32x4 acc[8][4];
#pragma unroll
  for (int m = 0; m < 8; ++m)
#pragma unroll
    for (int n = 0; n < 4; ++n) acc[m][n] = (f32x4){0.f, 0.f, 0.f, 0.f};

#define SLOT_A(kh, db) (ldsc + ((kh) * 2 + (db)) * 16384)
#define SLOT_B(kh, db) (ldsc + 65536 + ((kh) * 2 + (db)) * 16384)
#define STAGE_A(tk, kh, db) do { \
    char* _d = SLOT_A(kh, db) + wave * 1024; \
    size_t _k = (size_t)(tk) * 64 + (kh) * 32; \
    __builtin_amdgcn_global_load_lds((g_void*)(A + eA0 + _k), (lds_void*)_d, 16, 0, 0); \
    __builtin_amdgcn_global_load_lds((g_void*)(A + eA1 + _k), (lds_void*)(_d + 8192), 16, 0, 0); \
  } while (0)
#define STAGE_B(tk, kh, db) do { \
    char* _d = SLOT_B(kh, db) + wave * 1024; \
    size_t _k = (size_t)(tk) * 64 + (kh) * 32; \
    __builtin_amdgcn_global_load_lds((g_void*)(Bt + eB0 + _k), (lds_void*)_d, 16, 0, 0); \
    __builtin_amdgcn_global_load_lds((g_void*)(Bt + eB1 + _k), (lds_void*)(_d + 8192), 16, 0, 0); \
  } while (0)
#define LDA4(base, o) do { _Pragma("unroll") for (int m = 0; m < 4; ++m) \
    af[m] = *reinterpret_cast<const bf16x8*>((base) + aoff[(o) + m]); } while (0)
#define LDB4(base) do { _Pragma("unroll") for (int n = 0; n < 4; ++n) \
    bf[n] = *reinterpret_cast<const bf16x8*>((base) + boff[n]); } while (0)
#define MFMA_BLOCK(MB) do { _Pragma("unroll") for (int m = 0; m < 4; ++m) \
  _Pragma("unroll") for (int n = 0; n < 4; ++n) \
    acc[(MB) + m][n] = __builtin_amdgcn_mfma_f32_16x16x32_bf16(af[m], bf[n], acc[(MB) + m][n], 0, 0, 0); \
  } while (0)
#define BARX() __builtin_amdgcn_s_barrier()
#define LGKM0() asm volatile("s_waitcnt lgkmcnt(0)" ::: "memory")
#define VM8() asm volatile("s_waitcnt vmcnt(8)" ::: "memory")

  // prologue: tile0 both halves + tile1 kh0
  STAGE_A(0, 0, 0); STAGE_B(0, 0, 0);
  STAGE_A(0, 1, 0); STAGE_B(0, 1, 0);
  STAGE_A(1, 0, 1); STAGE_B(1, 0, 1);
  VM8();
  BARX();

  bf16x8 af[4], bf[4];
  for (int t = 0; t < NT; ++t) {
    int d = t & 1, nd = d ^ 1;
    int tk1 = (t + 1 < NT) ? t + 1 : NT - 1;   // clamped targets write never-read slots
    int tk2 = (t + 2 < NT) ? t + 2 : NT - 1;
    const char* Ak0 = SLOT_A(0, d); const char* Bk0 = SLOT_B(0, d);
    const char* Ak1 = SLOT_A(1, d); const char* Bk1 = SLOT_B(1, d);
    // P1: kk0, m0-3
    LDA4(Ak0, 0); LDB4(Bk0);
    STAGE_A(tk1, 1, nd);
    BARX(); LGKM0();
    __builtin_amdgcn_s_setprio(1); MFMA_BLOCK(0); __builtin_amdgcn_s_setprio(0);
    BARX();
    // P2: kk0, m4-7 (reuse bf)
    LDA4(Ak0, 4);
    STAGE_B(tk1, 1, nd);
    BARX(); LGKM0();
    __builtin_amdgcn_s_setprio(1); MFMA_BLOCK(4); __builtin_amdgcn_s_setprio(0);
    VM8(); BARX();
    // P3: kk1, m0-3
    LDA4(Ak1, 0); LDB4(Bk1);
    STAGE_A(tk2, 0, d);
    BARX(); LGKM0();
    __builtin_amdgcn_s_setprio(1); MFMA_BLOCK(0); __builtin_amdgcn_s_setprio(0);
    BARX();
    // P4: kk1, m4-7
    LDA4(Ak1, 4);
    STAGE_B(tk2, 0, d);
    BARX(); LGKM0();
    __builtin_amdgcn_s_setprio(1); MFMA_BLOCK(4); __builtin_amdgcn_s_setprio(0);
    VM8(); BARX();
  }
  asm volatile("s_waitcnt vmcnt(0)" ::: "memory");

  // epilogue: raw bf16 C store (R6 verbatim)
#pragma unroll
  for (int m = 0; m < 8; ++m)
#pragma unroll
    for (int n = 0; n < 4; ++n) {
      int col = n0 + wc * 64 + n * 16 + l15;
      size_t rb = (size_t)(m0 + wr * 128 + m * 16 + l4 * 4) * NG + col;
#pragma unroll
      for (int v = 0; v < 4; ++v)
        C[rb + (size_t)v * NG] = f2bf(acc[m][n][v]);
    }
#undef SLOT_A
#undef SLOT_B
#undef STAGE_A
#undef STAGE_B
#undef LDA4
#undef LDB4
#undef MFMA_BLOCK
}

// ---------------- shared span-embed core (R6 combine2 math) ----------------
__device__ __forceinline__ void span_embed(const ushort* __restrict__ PQR,
                                           const float* __restrict__ bias,
                                           int s, int len, int lane, float x[3][4]) {
  int e = s + len;
  float inv = 1.0f / (float)len;
  float acc0[3][4], accr[3][4];
  const ushort* Pr = PQR + (size_t)s * NG;
  const ushort* Qr = PQR + (size_t)(e - 1) * NG + 768;
#pragma unroll
  for (int c = 0; c < 3; ++c) {
    int h = c * 256 + lane * 4;
    ushort4 p = *(const ushort4*)(Pr + h);
    ushort4 q = *(const ushort4*)(Qr + h);
    acc0[c][0] = bf2f(p.x) + bf2f(q.x);
    acc0[c][1] = bf2f(p.y) + bf2f(q.y);
    acc0[c][2] = bf2f(p.z) + bf2f(q.z);
    acc0[c][3] = bf2f(p.w) + bf2f(q.w);
    accr[c][0] = accr[c][1] = accr[c][2] = accr[c][3] = 0.f;
  }
  for (int r = s; r < e; ++r) {
    const ushort* Rr = PQR + (size_t)r * NG + 1536;
#pragma unroll
    for (int c = 0; c < 3; ++c) {
      int h = c * 256 + lane * 4;
      ushort4 rv = *(const ushort4*)(Rr + h);
      accr[c][0] += bf2f(rv.x); accr[c][1] += bf2f(rv.y);
      accr[c][2] += bf2f(rv.z); accr[c][3] += bf2f(rv.w);
    }
  }
#pragma unroll
  for (int c = 0; c < 3; ++c) {
    int h = c * 256 + lane * 4;
    float4 bv = *(const float4*)(bias + h);
    x[c][0] = gelu_f(acc0[c][0] + accr[c][0] * inv + bv.x);
    x[c][1] = gelu_f(acc0[c][1] + accr[c][1] * inv + bv.y);
    x[c][2] = gelu_f(acc0[c][2] + accr[c][2] * inv + bv.z);
    x[c][3] = gelu_f(acc0[c][3] + accr[c][3] * inv + bv.w);
  }
}

// ---------------- support combine (R10 verbatim): writes embS ----------------
__global__ __launch_bounds__(256) void combine_sup(const ushort* __restrict__ PQR,
                                                   const int2* __restrict__ sortedS,
                                                   const float* __restrict__ bias,
                                                   ushort* __restrict__ embS) {
  int b = blockIdx.x;                        // 8192 blocks
  int sb = ((b & 7) << 10) + (b >> 3);       // XCD-contiguous chunks of 1024 blocks
  int wave = threadIdx.x >> 6, lane = threadIdx.x & 63;
  int wid = sb * 4 + wave;                   // 0..32767
  int2 rec = sortedS[wid];
  int s = rec.x, len = rec.y & 31, orig = rec.y >> 5;
  float x[3][4];
  span_embed(PQR, bias, s, len, lane, x);
  ushort* er = embS + (size_t)orig * H_DIM;
#pragma unroll
  for (int c = 0; c < 3; ++c) {
    int h = c * 256 + lane * 4;
    ushort4 o;
    o.x = f2bf(x[c][0]); o.y = f2bf(x[c][1]); o.z = f2bf(x[c][2]); o.w = f2bf(x[c][3]);
    *(ushort4*)(er + h) = o;
  }
}

// ---------------- proto accumulation: 1024 blocks x 32 spans ----------------
__global__ void proto_accum(const ushort* __restrict__ supEmb, const int* __restrict__ labels,
                            float* __restrict__ pSum, float* __restrict__ pCnt) {
  __shared__ float ls[C_CLS * H_DIM];
  __shared__ int lc[C_CLS];
  int t = threadIdx.x;
  for (int i = t; i < C_CLS * H_DIM; i += 256) ls[i] = 0.f;
  if (t < C_CLS) lc[t] = 0;
  __syncthreads();
  int base = blockIdx.x * 32;
  for (int si = 0; si < 32; ++si) {
    int sp = base + si;
    int lab = labels[sp];
    const ushort* er = supEmb + (size_t)sp * H_DIM;
#pragma unroll
    for (int j = 0; j < 3; ++j) {
      int c = t + j * 256;
      ls[lab * H_DIM + c] += bf2f(er[c]);
    }
    if (t == 0) lc[lab]++;
  }
  __syncthreads();
  for (int i = t; i < C_CLS * H_DIM; i += 256) atomicAdd(&pSum[i], ls[i]);
  if (t < C_CLS) atomicAdd(&pCnt[t], (float)lc[t]);
}

// ---------------- proto normalize (1 block) ----------------
__global__ void proto_norm(const float* __restrict__ pSum, const float* __restrict__ pCnt,
                           float* __restrict__ pN) {
  __shared__ float red[4];
  int t = threadIdx.x, lane = t & 63, wave = t >> 6;
  for (int c = 0; c < C_CLS; ++c) {
    float cnt = pCnt[c];
    float x[3];
#pragma unroll
    for (int j = 0; j < 3; ++j) {
      int h = t + j * 256;
      float v;
      if (cnt > 0.5f) v = pSum[c * H_DIM + h] / cnt;
      else {
        float gs = 0.f;
        for (int cc = 0; cc < C_CLS; ++cc) gs += pSum[cc * H_DIM + h];
        v = gs / (float)N_SUP;
      }
      x[j] = v;
    }
    float ss = x[0] * x[0] + x[1] * x[1] + x[2] * x[2];
#pragma unroll
    for (int o = 32; o; o >>= 1) ss += __shfl_xor(ss, o);
    if (lane == 0) red[wave] = ss;
    __syncthreads();
    float tot = red[0] + red[1] + red[2] + red[3];
    float inv = 1.0f / fmaxf(sqrtf(tot), 1e-12f);
#pragma unroll
    for (int j = 0; j < 3; ++j) pN[c * H_DIM + t + j * 256] = x[j] * inv;
    __syncthreads();
  }
}

// ---------------- query: embed + sim fused (R10 verbatim) ----------------
__global__ __launch_bounds__(256) void combine_qry_sim(const ushort* __restrict__ PQR,
                                                       const int2* __restrict__ sortedQ,
                                                       const float* __restrict__ bias,
                                                       const float* __restrict__ pN,
                                                       float* __restrict__ out) {
  __shared__ float lp[C_CLS * H_DIM];
  int b = blockIdx.x;                        // 8192 blocks
  int sb = ((b & 7) << 10) + (b >> 3);       // XCD-contiguous chunks of 1024 blocks
  int t = threadIdx.x, lane = t & 63, wave = t >> 6;
  for (int i = t; i < C_CLS * H_DIM; i += 256) lp[i] = pN[i];
  __syncthreads();
  int wid = sb * 4 + wave;                   // 0..32767
  int2 rec = sortedQ[wid];
  int s = rec.x, len = rec.y & 31, orig = rec.y >> 5;
  float x[3][4];
  span_embed(PQR, bias, s, len, lane, x);
  float sq = 0.f;
  float dot[C_CLS];
#pragma unroll
  for (int p = 0; p < C_CLS; ++p) dot[p] = 0.f;
#pragma unroll
  for (int c = 0; c < 3; ++c) {
    int h = c * 256 + lane * 4;
    sq += x[c][0] * x[c][0] + x[c][1] * x[c][1] + x[c][2] * x[c][2] + x[c][3] * x[c][3];
#pragma unroll
    for (int p = 0; p < C_CLS; ++p) {
      float4 pv = *(const float4*)(lp + p * H_DIM + h);
      dot[p] += x[c][0] * pv.x + x[c][1] * pv.y + x[c][2] * pv.z + x[c][3] * pv.w;
    }
  }
#pragma unroll
  for (int o = 32; o; o >>= 1) {
    sq += __shfl_xor(sq, o);
#pragma unroll
    for (int p = 0; p < C_CLS; ++p) dot[p] += __shfl_xor(dot[p], o);
  }
  if (lane == 0) {
    float inv = 1.0f / fmaxf(sqrtf(sq), 1e-12f);
    float* o = out + (size_t)orig * (C_CLS + 1);
    o[0] = dot[0] * inv; o[1] = dot[1] * inv; o[2] = dot[2] * inv;
    o[3] = dot[3] * inv; o[4] = dot[4] * inv; o[5] = dot[5] * inv;
    o[6] = dot[6] * inv; o[7] = dot[7] * inv; o[8] = dot[8] * inv;
    o[9] = dot[9] * inv; o[10] = 0.5f;
  }
}

extern "C" void kernel_launch(void* const* d_in, const int* in_sizes, int n_in,
                              void* d_out, int out_size, void* d_ws, size_t ws_size,
                              hipStream_t stream) {
  const float* token_emb = (const float*)d_in[0];
  const int*   spansS    = (const int*)d_in[1];
  const int*   labels    = (const int*)d_in[2];
  const int*   spansQ    = (const int*)d_in[3];
  const float* W         = (const float*)d_in[4];
  const float* b         = (const float*)d_in[5];
  float* out = (float*)d_out;

  char* ws = (char*)d_ws;
  size_t pqrB = (size_t)M_TOT * NG * 2;        // 301,989,888
  size_t tbB  = (size_t)M_TOT * H_DIM * 2;     // 100,663,296
  size_t wtB  = (size_t)NG * KG * 2;           //   3,538,944
  ushort* PQR  = (ushort*)ws;
  ushort* tebf = (ushort*)(ws + pqrB);         // dead after gemm8
  ushort* embS = tebf;                          // support embeddings alias tebf
  ushort* Bt   = (ushort*)(ws + pqrB + tbB);
  char*   tail = ws + pqrB + tbB + wtB;
  float*  pSum = (float*)tail;                                  // 7680 f
  float*  pCnt = pSum + C_CLS * H_DIM;                          // 64 f
  float*  pN   = pCnt + 64;                                     // 7680 f
  int*    histS = (int*)(pN + C_CLS * H_DIM);                   // 1024
  int*    histQ = histS + NBUCK;                                // 1024
  int*    curS  = histQ + NBUCK;                                // 1024
  int*    curQ  = curS + NBUCK;                                 // 1024
  int2*   sortedS = (int2*)(curQ + NBUCK);                      // 32768 int2
  int2*   sortedQ = sortedS + N_SUP;                            // 32768 int2

  hipMemsetAsync(pSum, 0, (C_CLS * H_DIM + 64) * sizeof(float), stream);
  hipMemsetAsync(histS, 0, 2 * NBUCK * sizeof(int), stream);
  prep_kernel<<<31552, 256, 0, stream>>>(token_emb, W, spansS, spansQ, tebf, Bt, histS, histQ);
  prefix2_kernel<<<1, NBUCK, 0, stream>>>(histS, histQ, curS, curQ);
  scatter2_kernel<<<64, 256, 0, stream>>>(spansS, spansQ, curS, curQ, sortedS, sortedQ);
  gemm8<<<2304, 512, 0, stream>>>(tebf, Bt, PQR);
  combine_sup<<<8192, 256, 0, stream>>>(PQR, sortedS, b, embS);
  proto_accum<<<N_SUP / 32, 256, 0, stream>>>(embS, labels, pSum, pCnt);
  proto_norm<<<1, 256, 0, stream>>>(pSum, pCnt, pN);
  combine_qry_sim<<<8192, 256, 0, stream>>>(PQR, sortedQ, b, pN, out);
}